// Round 9
// baseline (147.151 us; speedup 1.0000x reference)
//
#include <hip/hip_runtime.h>
#include <hip/hip_bf16.h>
#include <stdint.h>

// ---------------------------------------------------------------------------
// coAttention: out = V_i + V_t + 0.5*V_c + 0.5*V_e
// V = softmax_n( sum_k tanh(feat@W)[n,k]*wp[K+k] + bias[n] ) @ feat.
// Query half of tanh-concat cancels in softmax -> 4 independent stages:
// c(N=20), e(30), i(49), t(128); B=256, D=1024, K=256.
// M = B*N: 5120/7680/12544/32768 -> 32-row tiles: 160/240/392/1024 = 1816.
//
// R8: the 8-round invariant is A-delivery at ~2.1 TB/s regardless of
// structure; every variant read A as 256B-per-row slices strided 4KB
// (DRAM page scatter + tiny in-flight windows). Fix: block = 32 rows x
// FULL K in LDS (64KB bf16). Staging = 32x global_load_dwordx4 over a
// CONTIGUOUS 128KB region (1 row/instr, 32 loads in flight). Then a
// barrier-free 64-step K-loop: A from LDS, B frag-native from L2
// (R3-verified 32x32x16 path). 2 blocks/CU.
// ---------------------------------------------------------------------------

#define D_DIM 1024
#define K_OUT 256
#define MB 32

typedef float f32x4 __attribute__((ext_vector_type(4)));
typedef float f32x16 __attribute__((ext_vector_type(16)));
typedef short bf16x8 __attribute__((ext_vector_type(8)));
typedef unsigned short u16x8 __attribute__((ext_vector_type(8)));

static __device__ __forceinline__ unsigned short f2bf(float f) {
    return __builtin_bit_cast(unsigned short, __float2bfloat16(f));
}

// tanh(x) = 1 - 2/(exp(2x)+1); stable at +/-inf.
static __device__ __forceinline__ float fast_tanh(float x) {
    float e = __expf(2.0f * x);
    return 1.0f - 2.0f / (e + 1.0f);
}

// ---------------------------------------------------------------------------
// Kernel 1: W (f32 [1024][256]) -> frag-native bf16:
// ushort off = kblk*4096 + col*16 + half*8 + j, where k = kblk*16+half*8+j.
// ---------------------------------------------------------------------------
__global__ __launch_bounds__(256) void convert_wt(
    const float* __restrict__ w_c, const float* __restrict__ w_e,
    const float* __restrict__ w_i, const float* __restrict__ w_t,
    unsigned short* __restrict__ wtf)
{
    const float* wsel[4] = {w_c, w_e, w_i, w_t};
    const float* W = wsel[blockIdx.x];
    unsigned short* out = wtf + (size_t)blockIdx.x * (K_OUT * D_DIM);
    const int kb = blockIdx.y;          // 0..63
    const int t = threadIdx.x;          // col 0..255

    unsigned short tmp[16];
#pragma unroll
    for (int j = 0; j < 16; ++j)
        tmp[j] = f2bf(W[(size_t)(kb * 16 + j) * K_OUT + t]);   // coalesced over t

    u16x8 lo, hi;
#pragma unroll
    for (int j = 0; j < 8; ++j) { lo[j] = tmp[j]; hi[j] = tmp[8 + j]; }
    unsigned short* dst = out + (size_t)kb * 4096 + t * 16;
    *reinterpret_cast<u16x8*>(dst) = lo;
    *reinterpret_cast<u16x8*>(dst + 8) = hi;
}

// ---------------------------------------------------------------------------
// Kernel 2: fused logits GEMM. Block = 32 rows x 256 cols x K=1024.
// 256 thr = 4 waves; wave wv owns cols wv*64..+63 (2 col-tiles of 32).
// A: LDS-resident bf16 [32][1024], row stride 2048B, 16B chunks swizzled
//    by p = c ^ (row&7). Staged linearly (instr j = row j, contiguous).
// B: frag-native bf16 from L2 (verified layout).  MFMA 32x32x16.
// s[m] = sum_col tanh(proj[m,col]) * wp[256+col].
// ---------------------------------------------------------------------------
struct GemmStage {
    const float* feat;          // [M][1024] f32
    const unsigned short* wt;   // frag-native bf16, 256K ushorts
    const float* wp;            // [512] f32 (use [256..])
    float* s_out;               // [M]
    int blk_start;              // in 32-row tiles
};

__global__ __launch_bounds__(256, 2) void logits_gemm(
    GemmStage g0, GemmStage g1, GemmStage g2, GemmStage g3)
{
    __shared__ __align__(16) unsigned char As[MB * 2048];   // 64 KB
    __shared__ float partial[MB][4];

    const int bid = blockIdx.x;
    GemmStage st;
    if (bid < g1.blk_start) st = g0;
    else if (bid < g2.blk_start) st = g1;
    else if (bid < g3.blk_start) st = g2;
    else st = g3;
    const int m0 = (bid - st.blk_start) * MB;

    const int t = threadIdx.x;
    const int wv = t >> 6, lane = t & 63;
    const int l31 = lane & 31, lh = lane >> 5;

    // ---- A staging: instr j reads row j; thread t reads f32 cols t*4..+4 ----
    // Per instr: 256 thr x 16B = 4KB = exactly one row -> block region is a
    // single contiguous 128KB stream; 32 independent loads in flight.
    const float* ab = st.feat + (size_t)m0 * D_DIM + t * 4;
    f32x4 stg[32];
#pragma unroll 32
    for (int j = 0; j < 32; ++j)
        stg[j] = *reinterpret_cast<const f32x4*>(ab + (size_t)j * D_DIM);

    // cvt + swizzled ds_write_b64: row j, 16B-chunk c = t>>1, sub (t&1)*8
#pragma unroll 32
    for (int j = 0; j < 32; ++j) {
        unsigned long long o;
        unsigned short* op = reinterpret_cast<unsigned short*>(&o);
#pragma unroll
        for (int x = 0; x < 4; ++x) op[x] = f2bf(stg[j][x]);
        const int p = (t >> 1) ^ (j & 7);
        *reinterpret_cast<unsigned long long*>(&As[j * 2048 + p * 16 + (t & 1) * 8]) = o;
    }
    __syncthreads();

    // ---- K-loop: barrier-free; A from LDS, B dense from L2 ----
    // B: col = wv*64 + ct*32 + l31, k = kk*16 + lh*8 + j
    //    ushort off = kk*4096 + col*16 + lh*8 ; ct -> +512
    const unsigned short* wtb = st.wt + ((wv * 64 + l31) << 4) + lh * 8;

    f32x16 a0 = (f32x16)(0.f), a1 = (f32x16)(0.f);

#pragma unroll 4
    for (int kk = 0; kk < 64; ++kk) {
        const bf16x8 af = *reinterpret_cast<const bf16x8*>(
            &As[l31 * 2048 + (((kk * 2 + lh) ^ (l31 & 7)) << 4)]);
        const u16x8 b0 = *reinterpret_cast<const u16x8*>(wtb + kk * 4096);
        const u16x8 b1 = *reinterpret_cast<const u16x8*>(wtb + kk * 4096 + 512);
        a0 = __builtin_amdgcn_mfma_f32_32x32x16_bf16(
            af, __builtin_bit_cast(bf16x8, b0), a0, 0, 0, 0);
        a1 = __builtin_amdgcn_mfma_f32_32x32x16_bf16(
            af, __builtin_bit_cast(bf16x8, b1), a1, 0, 0, 0);
    }

    // ---- epilogue: tanh * wp2, reduce 64 cols/wave -> partial -> s_out ----
    // C/D 32x32: col = l31 (+wv*64+ct*32), row = (r&3) + 8*(r>>2) + 4*lh
    const float wp0 = st.wp[K_OUT + wv * 64 + l31];
    const float wp1 = st.wp[K_OUT + wv * 64 + 32 + l31];

#pragma unroll
    for (int r = 0; r < 16; ++r) {
        float v = fast_tanh(a0[r]) * wp0 + fast_tanh(a1[r]) * wp1;
        v += __shfl_xor(v, 1);
        v += __shfl_xor(v, 2);
        v += __shfl_xor(v, 4);
        v += __shfl_xor(v, 8);
        v += __shfl_xor(v, 16);
        if (l31 == 0) partial[(r & 3) + 8 * (r >> 2) + 4 * lh][wv] = v;
    }
    __syncthreads();
    if (t < MB)
        st.s_out[m0 + t] = partial[t][0] + partial[t][1] + partial[t][2] + partial[t][3];
}

// ---------------------------------------------------------------------------
// Kernel 3: per (b, stage): softmax over N logits (+bias), then V = P @ feat.
// ---------------------------------------------------------------------------
struct PVStage {
    const float* s;       // [B*N]
    const float* bias;    // [N]
    const float* feat;    // [B*N][1024]
    float* v_out;         // [B][1024]
    int N;
};

__global__ __launch_bounds__(256) void softmax_pv(
    PVStage p0, PVStage p1, PVStage p2, PVStage p3)
{
    PVStage st = (blockIdx.y == 0) ? p0 : (blockIdx.y == 1) ? p1
               : (blockIdx.y == 2) ? p2 : p3;
    const int b = blockIdx.x, t = threadIdx.x;
    const int N = st.N;

    __shared__ float P[128];
    __shared__ float inv_s;

    if (t < N) P[t] = st.s[b * N + t] + st.bias[t];
    __syncthreads();
    if (t < 64) {
        float m = -3.4e38f;
        for (int n = t; n < N; n += 64) m = fmaxf(m, P[n]);
#pragma unroll
        for (int sh = 32; sh; sh >>= 1) m = fmaxf(m, __shfl_xor(m, sh));
        float ssum = 0.f;
        for (int n = t; n < N; n += 64) { float e = __expf(P[n] - m); P[n] = e; ssum += e; }
#pragma unroll
        for (int sh = 32; sh; sh >>= 1) ssum += __shfl_xor(ssum, sh);
        if (t == 0) inv_s = 1.0f / ssum;
    }
    __syncthreads();
    const float inv = inv_s;

    f32x4 accv = (f32x4){0.f, 0.f, 0.f, 0.f};
    const float* fb = st.feat + (size_t)b * N * D_DIM + t * 4;
    for (int n = 0; n < N; ++n) {
        f32x4 f = *reinterpret_cast<const f32x4*>(fb + (size_t)n * D_DIM);
        accv += (P[n] * inv) * f;
    }
    *reinterpret_cast<f32x4*>(&st.v_out[(size_t)b * D_DIM + t * 4]) = accv;
}

// ---------------------------------------------------------------------------
// Kernel 4: out = V_i + V_t + 0.5*V_c + 0.5*V_e
// ---------------------------------------------------------------------------
__global__ __launch_bounds__(256) void combine_out(
    const float* __restrict__ vc, const float* __restrict__ ve,
    const float* __restrict__ vi, const float* __restrict__ vt,
    float* __restrict__ out)
{
    const int i = (blockIdx.x * 256 + threadIdx.x) * 4;
    f32x4 a = *reinterpret_cast<const f32x4*>(vi + i);
    f32x4 bb = *reinterpret_cast<const f32x4*>(vt + i);
    f32x4 c = *reinterpret_cast<const f32x4*>(vc + i);
    f32x4 e = *reinterpret_cast<const f32x4*>(ve + i);
    *reinterpret_cast<f32x4*>(out + i) = a + bb + 0.5f * c + 0.5f * e;
}

// ---------------------------------------------------------------------------
extern "C" void kernel_launch(void* const* d_in, const int* in_sizes, int n_in,
                              void* d_out, int out_size, void* d_ws, size_t ws_size,
                              hipStream_t stream)
{
    const float* ifeature = (const float*)d_in[0];   // (256,49,1024)
    const float* tfeature = (const float*)d_in[1];   // (256,128,1024)
    const float* cfeature = (const float*)d_in[2];   // (256,20,1024)
    const float* efeature = (const float*)d_in[3];   // (256,30,1024)
    const float* w_Vc = (const float*)d_in[5];
    const float* w_Pc = (const float*)d_in[6];
    const float* b_Pc = (const float*)d_in[7];
    const float* w_Ve = (const float*)d_in[8];
    const float* w_Pe = (const float*)d_in[9];
    const float* b_Pe = (const float*)d_in[10];
    const float* w_Vi = (const float*)d_in[11];
    const float* w_Pi = (const float*)d_in[13];
    const float* b_Pi = (const float*)d_in[14];
    const float* w_Vt = (const float*)d_in[16];
    const float* w_Pt = (const float*)d_in[17];
    const float* b_Pt = (const float*)d_in[18];

    // workspace layout (~7 MB)
    char* ws = (char*)d_ws;
    unsigned short* wtf = (unsigned short*)ws;                // 4 x 512KB bf16
    float* s_c = (float*)(ws + 2u * 1024 * 1024);             // 5120
    float* s_e = s_c + 5120;                                  // 7680
    float* s_i = s_e + 7680;                                  // 12544
    float* s_t = s_i + 12544;                                 // 32768
    float* v_c = (float*)(ws + 3u * 1024 * 1024);             // 4 x 1MB
    float* v_e = v_c + 256 * 1024;
    float* v_i = v_e + 256 * 1024;
    float* v_t = v_i + 256 * 1024;

    convert_wt<<<dim3(4, 64), 256, 0, stream>>>(w_Vc, w_Ve, w_Vi, w_Vt, wtf);

    // 32-row tiles: c=160, e=240, i=392, t=1024 -> 1816 blocks
    GemmStage g0{cfeature, wtf,          w_Pc, s_c, 0};
    GemmStage g1{efeature, wtf + 262144, w_Pe, s_e, 160};
    GemmStage g2{ifeature, wtf + 524288, w_Pi, s_i, 400};
    GemmStage g3{tfeature, wtf + 786432, w_Pt, s_t, 792};
    logits_gemm<<<1816, 256, 0, stream>>>(g0, g1, g2, g3);

    PVStage p0{s_c, b_Pc, cfeature, v_c, 20};
    PVStage p1{s_e, b_Pe, efeature, v_e, 30};
    PVStage p2{s_i, b_Pi, ifeature, v_i, 49};
    PVStage p3{s_t, b_Pt, tfeature, v_t, 128};
    softmax_pv<<<dim3(256, 4), 256, 0, stream>>>(p0, p1, p2, p3);

    combine_out<<<256, 256, 0, stream>>>(v_c, v_e, v_i, v_t, (float*)d_out);
}